// Round 5
// baseline (226.948 us; speedup 1.0000x reference)
//
#include <hip/hip_runtime.h>

#define ALPHA_F 1000.0f

typedef _Float16 half8 __attribute__((ext_vector_type(8)));
typedef float floatx4 __attribute__((ext_vector_type(4)));

// ============ pre-split W_enc (scaled x256) into fp16 hi/lo, frag-order =====
// idx = ((kc*16 + nt)*64 + lane)*8 + j ; lane=(n&15)|(((k>>3)&3)<<4), j=k&7
__global__ __launch_bounds__(256) void split_wenc(
    const float* __restrict__ W, _Float16* __restrict__ Wh, _Float16* __restrict__ Wl)
{
    const int q = blockIdx.x * 256 + threadIdx.x;   // 65536 threads
    const int n = q & 255, k8 = q >> 8;             // k8: 0..255
    const int k = k8 * 8;
    half8 h, l;
    #pragma unroll
    for (int i = 0; i < 8; ++i) {
        const float v = W[(size_t)(k + i) * 256 + n] * 256.0f;
        const _Float16 hi = (_Float16)v;
        h[i] = hi;
        l[i] = (_Float16)(v - (float)hi);
    }
    const int kc = k >> 5, nt = n >> 4;
    const int lane = (n & 15) | ((k8 & 3) << 4);
    const size_t idx = (size_t)((kc * 16 + nt) * 64 + lane) * 8;
    *(half8*)(Wh + idx) = h;
    *(half8*)(Wl + idx) = l;
}

// ============ pre-split W_dec into fp16 hi, frag-order ======================
__global__ __launch_bounds__(256) void split_wdec(
    const float* __restrict__ W, _Float16* __restrict__ Wh)
{
    const int q = blockIdx.x * 256 + threadIdx.x;   // 65536 threads
    const int n = q & 2047, k8 = q >> 11;           // k8: 0..31
    const int k = k8 * 8;
    half8 h;
    #pragma unroll
    for (int i = 0; i < 8; ++i) h[i] = (_Float16)W[(size_t)(k + i) * 2048 + n];
    const int kc = k8 >> 2, nt = n >> 4;
    const int lane = (n & 15) | ((k8 & 3) << 4);
    *(half8*)(Wh + (size_t)((kc * 128 + nt) * 64 + lane) * 8) = h;
}

// ============ pre-split creps into fp16 hi + scaled lo (x2048), frag-order ==
__global__ __launch_bounds__(256) void split_creps(
    const float* __restrict__ C, _Float16* __restrict__ Ch, _Float16* __restrict__ Cl)
{
    const int q = blockIdx.x * 256 + threadIdx.x;   // 8192 threads
    const int n = q & 255, j8 = q >> 8;             // j8: 0..31
    const int j = j8 * 8;
    half8 h, l;
    #pragma unroll
    for (int i = 0; i < 8; ++i) {
        const float v = C[(size_t)n * 256 + j + i];
        const _Float16 hi = (_Float16)v;
        h[i] = hi;
        l[i] = (_Float16)((v - (float)hi) * 2048.0f);
    }
    const int jc = j >> 5, nt = n >> 4;
    const int lane = (n & 15) | ((j8 & 3) << 4);
    const size_t idx = (size_t)((jc * 16 + nt) * 64 + lane) * 8;
    *(half8*)(Ch + idx) = h;
    *(half8*)(Cl + idx) = l;
}

// ============ emb partials, barrier-free register pipeline ==================
// split-K=4, grid (4, 128). BM=64, BN=256, BK=32 per iter, 16 iters.
// No LDS, no __syncthreads. A-frags loaded per-lane from x and split in regs
// (all 4 waves share the same 8KB x slice -> L1). B-frags loaded coalesced
// (lane*16B) from frag-ordered Wh/Wl in L2.
// P layout: P[((kk*128+mb)*16 + (mi*4+ni))*1024 + t*4] float4, coalesced.
__global__ __launch_bounds__(256) void emb_gemm(
    const float* __restrict__ x, const _Float16* __restrict__ Wh,
    const _Float16* __restrict__ Wl, float* __restrict__ P)
{
    const int t = threadIdx.x, lane = t & 63, w = t >> 6;
    const int kk = blockIdx.x;        // K slice of 512
    const int mb = blockIdx.y;
    const int m0 = mb * 64;
    const int row16 = lane & 15, oct = lane >> 4;

    floatx4 acc[4][4] = {};

    const float* xBase = x + (size_t)(m0 + row16) * 2048 + kk * 512 + oct * 8;

    for (int it = 0; it < 16; ++it) {
        // A-frags: 4 m-tiles, fp32 -> hi/lo fp16 in registers
        half8 ah[4], al[4];
        #pragma unroll
        for (int mi = 0; mi < 4; ++mi) {
            const float* p = xBase + (size_t)(mi * 16) * 2048 + it * 32;
            const float4 u0 = *(const float4*)(p);
            const float4 u1 = *(const float4*)(p + 4);
            const float vv[8] = {u0.x, u0.y, u0.z, u0.w, u1.x, u1.y, u1.z, u1.w};
            #pragma unroll
            for (int i = 0; i < 8; ++i) {
                const _Float16 hi = (_Float16)vv[i];
                ah[mi][i] = hi;
                al[mi][i] = (_Float16)(vv[i] - (float)hi);
            }
        }
        const int kc = kk * 16 + it;
        const _Float16* bh_p = Wh + ((size_t)(kc * 16 + w * 4) * 64 + lane) * 8;
        const _Float16* bl_p = Wl + ((size_t)(kc * 16 + w * 4) * 64 + lane) * 8;
        #pragma unroll
        for (int ni = 0; ni < 4; ++ni) {
            const half8 bh = *(const half8*)(bh_p + (size_t)ni * 512);
            const half8 bl = *(const half8*)(bl_p + (size_t)ni * 512);
            #pragma unroll
            for (int mi = 0; mi < 4; ++mi) {
                acc[mi][ni] = __builtin_amdgcn_mfma_f32_16x16x32_f16(ah[mi], bl, acc[mi][ni], 0, 0, 0);
                acc[mi][ni] = __builtin_amdgcn_mfma_f32_16x16x32_f16(al[mi], bh, acc[mi][ni], 0, 0, 0);
                acc[mi][ni] = __builtin_amdgcn_mfma_f32_16x16x32_f16(ah[mi], bh, acc[mi][ni], 0, 0, 0);
            }
        }
    }

    // coalesced frag-dump: 16 dwordx4 stores, wave-contiguous
    float* Pb = P + ((size_t)(kk * 128 + mb) * 16) * 1024;
    #pragma unroll
    for (int mi = 0; mi < 4; ++mi)
        #pragma unroll
        for (int ni = 0; ni < 4; ++ni)
            *(floatx4*)(Pb + (size_t)(mi * 4 + ni) * 1024 + t * 4) = acc[mi][ni];
}

// ============ finalize: reduce split-K=4 frag-dump, +bias, emit =============
// grid 256: block b -> emb-block mb=b>>1, mi pair mi2=(b&1)*2 (32 rows).
__global__ __launch_bounds__(256) void finalize(
    const float* __restrict__ P, const float* __restrict__ b_enc,
    _Float16* __restrict__ eh, _Float16* __restrict__ el,
    float* __restrict__ enorm)
{
    __shared__ float femb[32 * 257];
    const int t = threadIdx.x, lane = t & 63, w = t >> 6;
    const int mb = blockIdx.x >> 1, half_ = blockIdx.x & 1;
    const int mi2 = half_ * 2;

    floatx4 acc[2][4] = {};
    #pragma unroll
    for (int kk = 0; kk < 4; ++kk) {
        const float* Pb = P + ((size_t)(kk * 128 + mb) * 16) * 1024;
        #pragma unroll
        for (int dmi = 0; dmi < 2; ++dmi)
            #pragma unroll
            for (int ni = 0; ni < 4; ++ni) {
                const floatx4 v = *(const floatx4*)(Pb + (size_t)((mi2 + dmi) * 4 + ni) * 1024 + t * 4);
                acc[dmi][ni] += v;
            }
    }

    const float inv = 1.0f / 256.0f;
    #pragma unroll
    for (int dmi = 0; dmi < 2; ++dmi) {
        #pragma unroll
        for (int ni = 0; ni < 4; ++ni) {
            const int col = w * 64 + ni * 16 + (lane & 15);
            const float bias = b_enc[col];
            const int rowL = dmi * 16 + (lane >> 4) * 4;
            #pragma unroll
            for (int r = 0; r < 4; ++r)
                femb[(rowL + r) * 257 + col] = acc[dmi][ni][r] * inv + bias;
        }
    }
    __syncthreads();

    // 32 rows x 32 octets, 4 octets per thread (same row)
    const int rowL = t >> 3;                  // 0..31
    float ssq = 0.0f;
    #pragma unroll
    for (int oo = 0; oo < 4; ++oo) {
        const int oid = t * 4 + oo;
        const int q = oid & 31;               // col octet
        const float* src = femb + rowL * 257 + q * 8;
        half8 h, l;
        #pragma unroll
        for (int i = 0; i < 8; ++i) {
            const float v = src[i];
            const _Float16 hi = (_Float16)v;
            h[i] = hi;
            l[i] = (_Float16)((v - (float)hi) * 2048.0f);
            ssq += v * v;
        }
        const int grow = mb * 64 + half_ * 32 + rowL;
        const size_t idx = (size_t)(((grow >> 4) * 8 + (q >> 2)) * 64
                                    + ((grow & 15) | ((q & 3) << 4))) * 8;
        *(half8*)(eh + idx) = h;
        *(half8*)(el + idx) = l;
    }
    ssq += __shfl_xor(ssq, 1, 64);
    ssq += __shfl_xor(ssq, 2, 64);
    ssq += __shfl_xor(ssq, 4, 64);
    if ((t & 7) == 0) enorm[mb * 64 + half_ * 32 + rowL] = ssq;
}

// ============ recon = emb @ W_dec + b_dec, barrier-free =====================
// grid (16, 64), 4 waves, wave tile 64x64. A (embh) and B (Wdh) frag-order
// in global (L2/L3-resident) -> direct register loads, no LDS.
__global__ __launch_bounds__(256) void recon_gemm(
    const _Float16* __restrict__ embh, const _Float16* __restrict__ Wdh,
    const float* __restrict__ b_dec, float* __restrict__ out)
{
    const int t = threadIdx.x, lane = t & 63, w = t >> 6;
    const int wm = w >> 1, wn = w & 1;
    const int nb = blockIdx.x, mb = blockIdx.y;

    floatx4 acc[4][4] = {};

    for (int kc = 0; kc < 8; ++kc) {
        half8 a[4];
        #pragma unroll
        for (int mi = 0; mi < 4; ++mi) {
            const int mt = mb * 8 + wm * 4 + mi;
            a[mi] = *(const half8*)(embh + (size_t)((mt * 8 + kc) * 64 + lane) * 8);
        }
        #pragma unroll
        for (int ni = 0; ni < 4; ++ni) {
            const half8 b = *(const half8*)(Wdh + (size_t)((kc * 128 + nb * 8 + wn * 4 + ni) * 64 + lane) * 8);
            #pragma unroll
            for (int mi = 0; mi < 4; ++mi)
                acc[mi][ni] = __builtin_amdgcn_mfma_f32_16x16x32_f16(a[mi], b, acc[mi][ni], 0, 0, 0);
        }
    }

    #pragma unroll
    for (int ni = 0; ni < 4; ++ni) {
        const int col = nb * 128 + (wn * 4 + ni) * 16 + (lane & 15);
        const float bias = b_dec[col];
        #pragma unroll
        for (int mi = 0; mi < 4; ++mi) {
            const int rowBase = mb * 128 + (wm * 4 + mi) * 16 + (lane >> 4) * 4;
            #pragma unroll
            for (int r = 0; r < 4; ++r)
                out[(size_t)(rowBase + r) * 2048 + col] = acc[mi][ni][r] + bias;
        }
    }
}

// ============ row sum-of-squares (creps -> cnorm), ncols=256 ================
__global__ __launch_bounds__(256) void row_sumsq(
    const float* __restrict__ src, float* __restrict__ dst)
{
    const int wid = threadIdx.x >> 6, lane = threadIdx.x & 63;
    const int row = blockIdx.x * 4 + wid;
    const float4 v = *(const float4*)(src + (size_t)row * 256 + lane * 4);
    float s = v.x * v.x + v.y * v.y + v.z * v.z + v.w * v.w;
    #pragma unroll
    for (int off = 32; off >= 1; off >>= 1) s += __shfl_xor(s, off, 64);
    if (lane == 0) dst[row] = s;
}

// ============ dist + softmin via fp16x3 MFMA, no LDS staging ================
__global__ __launch_bounds__(256) void dist_softmin(
    const _Float16* __restrict__ eh, const _Float16* __restrict__ el,
    const _Float16* __restrict__ ch, const _Float16* __restrict__ cl,
    const float* __restrict__ enorm, const float* __restrict__ cnorm,
    float* __restrict__ out)
{
    __shared__ float D[32 * 257];
    __shared__ float MINV[32], SUMV[32];
    const int t = threadIdx.x, lane = t & 63, w = t >> 6;
    const int b0 = blockIdx.x * 32;
    const int mt0 = blockIdx.x * 2;

    floatx4 acc[2][4] = {}, accX[2][4] = {};
    for (int kc = 0; kc < 8; ++kc) {
        half8 ah[2], al[2];
        #pragma unroll
        for (int mi = 0; mi < 2; ++mi) {
            const size_t ab = (size_t)(((mt0 + mi) * 8 + kc) * 64 + lane) * 8;
            ah[mi] = *(const half8*)(eh + ab);
            al[mi] = *(const half8*)(el + ab);
        }
        #pragma unroll
        for (int ni = 0; ni < 4; ++ni) {
            const size_t bb = (size_t)((kc * 16 + (w * 4 + ni)) * 64 + lane) * 8;
            const half8 bh = *(const half8*)(ch + bb);
            const half8 bl = *(const half8*)(cl + bb);
            #pragma unroll
            for (int mi = 0; mi < 2; ++mi) {
                acc[mi][ni]  = __builtin_amdgcn_mfma_f32_16x16x32_f16(ah[mi], bh, acc[mi][ni], 0, 0, 0);
                accX[mi][ni] = __builtin_amdgcn_mfma_f32_16x16x32_f16(ah[mi], bl, accX[mi][ni], 0, 0, 0);
                accX[mi][ni] = __builtin_amdgcn_mfma_f32_16x16x32_f16(al[mi], bh, accX[mi][ni], 0, 0, 0);
            }
        }
    }

    const float invs = 1.0f / 2048.0f;
    #pragma unroll
    for (int mi = 0; mi < 2; ++mi) {
        #pragma unroll
        for (int ni = 0; ni < 4; ++ni) {
            const int k = w * 64 + ni * 16 + (lane & 15);
            const float cn = cnorm[k];
            #pragma unroll
            for (int r = 0; r < 4; ++r) {
                const int rl = mi * 16 + (lane >> 4) * 4 + r;
                const float S = acc[mi][ni][r] + accX[mi][ni][r] * invs;
                D[rl * 257 + k] = enorm[b0 + rl] - 2.0f * S + cn;
            }
        }
    }
    __syncthreads();

    #pragma unroll
    for (int rr = 0; rr < 8; ++rr) {
        const int r = w * 8 + rr;
        const float d0 = D[r * 257 + lane +   0];
        const float d1 = D[r * 257 + lane +  64];
        const float d2 = D[r * 257 + lane + 128];
        const float d3 = D[r * 257 + lane + 192];
        float mn = fminf(fminf(d0, d1), fminf(d2, d3));
        #pragma unroll
        for (int off = 32; off >= 1; off >>= 1) mn = fminf(mn, __shfl_xor(mn, off, 64));
        float s = expf(-ALPHA_F * (d0 - mn)) + expf(-ALPHA_F * (d1 - mn))
                + expf(-ALPHA_F * (d2 - mn)) + expf(-ALPHA_F * (d3 - mn));
        #pragma unroll
        for (int off = 32; off >= 1; off >>= 1) s += __shfl_xor(s, off, 64);
        if (lane == 0) { MINV[r] = mn; SUMV[r] = s; }
    }
    __syncthreads();

    const int b = t & 31, kg = t >> 5;
    const float mn = MINV[b], sv = SUMV[b];
    #pragma unroll
    for (int kk = 0; kk < 32; ++kk) {
        const int k = kk * 8 + kg;
        const float dv = D[b * 257 + k];
        out[(size_t)k * 8192 + b0 + b] = dv * expf(-ALPHA_F * (dv - mn)) / sv;
    }
}

// ================= launch ==================================================
extern "C" void kernel_launch(void* const* d_in, const int* in_sizes, int n_in,
                              void* d_out, int out_size, void* d_ws, size_t ws_size,
                              hipStream_t stream) {
    const float* x     = (const float*)d_in[0];   // [8192,2048]
    const float* W_enc = (const float*)d_in[1];   // [2048,256]
    const float* b_enc = (const float*)d_in[2];   // [256]
    const float* W_dec = (const float*)d_in[3];   // [256,2048]
    const float* b_dec = (const float*)d_in[4];   // [2048]
    const float* creps = (const float*)d_in[5];   // [256,256]

    float* out_w   = (float*)d_out;               // [256,8192]
    float* out_rec = out_w + (size_t)256 * 8192;  // [8192,2048]
    float* P       = out_rec;                     // split-K frag-dump (32MB of 64MB)

    float*     enorm = (float*)d_ws;                       // 32 KB
    float*     cnorm = enorm + 8192;                       // 1 KB
    _Float16*  embh  = (_Float16*)(cnorm + 256);           // 4 MB, frag-order
    _Float16*  embl  = embh + (size_t)8192 * 256;          // 4 MB
    _Float16*  Whf   = embl + (size_t)8192 * 256;          // 1 MB
    _Float16*  Wlf   = Whf + (size_t)2048 * 256;           // 1 MB
    _Float16*  Wdh   = Wlf + (size_t)2048 * 256;           // 1 MB
    _Float16*  crh   = Wdh + (size_t)256 * 2048;           // 128 KB
    _Float16*  crl   = crh + (size_t)256 * 256;            // 128 KB

    split_wenc<<<256, 256, 0, stream>>>(W_enc, Whf, Wlf);
    split_wdec<<<256, 256, 0, stream>>>(W_dec, Wdh);
    split_creps<<<32, 256, 0, stream>>>(creps, crh, crl);
    row_sumsq<<<64, 256, 0, stream>>>(creps, cnorm);

    // emb partial sums (split-K=4, barrier-free) into out_rec scratch region
    emb_gemm<<<dim3(4, 128), 256, 0, stream>>>(x, Whf, Wlf, P);

    // reduce + bias -> embh/embl/enorm
    finalize<<<256, 256, 0, stream>>>(P, b_enc, embh, embl, enorm);

    // weighted_dist (output 0)
    dist_softmin<<<256, 256, 0, stream>>>(embh, embl, crh, crl, enorm, cnorm, out_w);

    // reconstruction (output 1) — overwrites the partials region
    recon_gemm<<<dim3(16, 64), 256, 0, stream>>>(embh, Wdh, b_dec, out_rec);
}

// Round 6
// 204.300 us; speedup vs baseline: 1.1109x; 1.1109x over previous
//
#include <hip/hip_runtime.h>

#define ALPHA_F 1000.0f

typedef _Float16 half8 __attribute__((ext_vector_type(8)));
typedef float floatx4 __attribute__((ext_vector_type(4)));

__device__ __forceinline__ void gload_lds16(const void* g, void* l) {
    __builtin_amdgcn_global_load_lds(
        (const __attribute__((address_space(1))) unsigned int*)g,
        (__attribute__((address_space(3))) unsigned int*)l, 16, 0, 0);
}

// ============ fused prep: W_enc/W_dec/creps splits + cnorm ==================
// blocks 0..255: split_wenc ; 256..511: split_wdec ; 512..543: split_creps ;
// 544..607: row_sumsq(creps)->cnorm.  Per-element code identical to r3.
__global__ __launch_bounds__(256) void prep(
    const float* __restrict__ W_enc, const float* __restrict__ W_dec,
    const float* __restrict__ creps,
    _Float16* __restrict__ Wh, _Float16* __restrict__ Wl,
    _Float16* __restrict__ Wdh,
    _Float16* __restrict__ Ch, _Float16* __restrict__ Cl,
    float* __restrict__ cnorm)
{
    const int bid = blockIdx.x;
    if (bid < 256) {
        const int q = bid * 256 + threadIdx.x;
        const int n = q & 255, k8 = q >> 8;
        const int k = k8 * 8;
        half8 h, l;
        #pragma unroll
        for (int i = 0; i < 8; ++i) {
            const float v = W_enc[(size_t)(k + i) * 256 + n] * 256.0f;
            const _Float16 hi = (_Float16)v;
            h[i] = hi;
            l[i] = (_Float16)(v - (float)hi);
        }
        const int kc = k >> 5, nt = n >> 4;
        const int lane = (n & 15) | ((k8 & 3) << 4);
        const size_t idx = (size_t)((kc * 16 + nt) * 64 + lane) * 8;
        *(half8*)(Wh + idx) = h;
        *(half8*)(Wl + idx) = l;
    } else if (bid < 512) {
        const int q = (bid - 256) * 256 + threadIdx.x;
        const int n = q & 2047, k8 = q >> 11;
        const int k = k8 * 8;
        half8 h;
        #pragma unroll
        for (int i = 0; i < 8; ++i) h[i] = (_Float16)W_dec[(size_t)(k + i) * 2048 + n];
        const int kc = k8 >> 2, nt = n >> 4;
        const int lane = (n & 15) | ((k8 & 3) << 4);
        *(half8*)(Wdh + (size_t)((kc * 128 + nt) * 64 + lane) * 8) = h;
    } else if (bid < 544) {
        const int q = (bid - 512) * 256 + threadIdx.x;
        const int n = q & 255, j8 = q >> 8;
        const int j = j8 * 8;
        half8 h, l;
        #pragma unroll
        for (int i = 0; i < 8; ++i) {
            const float v = creps[(size_t)n * 256 + j + i];
            const _Float16 hi = (_Float16)v;
            h[i] = hi;
            l[i] = (_Float16)((v - (float)hi) * 2048.0f);
        }
        const int jc = j >> 5, nt = n >> 4;
        const int lane = (n & 15) | ((j8 & 3) << 4);
        const size_t idx = (size_t)((jc * 16 + nt) * 64 + lane) * 8;
        *(half8*)(Ch + idx) = h;
        *(half8*)(Cl + idx) = l;
    } else {
        // cnorm: identical arithmetic to r3 row_sumsq (bit-critical!)
        const int wid = threadIdx.x >> 6, lane = threadIdx.x & 63;
        const int row = (bid - 544) * 4 + wid;
        const float4 v = *(const float4*)(creps + (size_t)row * 256 + lane * 4);
        float s = v.x * v.x + v.y * v.y + v.z * v.z + v.w * v.w;
        #pragma unroll
        for (int off = 32; off >= 1; off >>= 1) s += __shfl_xor(s, off, 64);
        if (lane == 0) cnorm[row] = s;
    }
}

// ============ emb partials (r3 verbatim — bit-validated, absmax 4.0) ========
// split-K=4, grid (4, 128). BM=64, BN=256, BK=32, 16 iters.
// P layout: row-major per partial, Pk[(row)*256 + col], kk-stride 2097152.
__global__ __launch_bounds__(256) void emb_gemm(
    const float* __restrict__ x, const _Float16* __restrict__ Wh,
    const _Float16* __restrict__ Wl, float* __restrict__ P)
{
    __shared__ _Float16 Ah[4 * 64 * 8], Al[4 * 64 * 8];   // 4KB each
    __shared__ _Float16 Bh[16 * 64 * 8], Bl[16 * 64 * 8]; // 16KB each
    const int t = threadIdx.x, lane = t & 63, w = t >> 6;
    const int kk = blockIdx.x;        // split-K chunk
    const int mb = blockIdx.y;
    const int m0 = mb * 64;

    const int am = t >> 2, q = t & 3;
    _Float16* AhW = Ah + (((am >> 4) * 64) + ((am & 15) | (q << 4))) * 8;
    _Float16* AlW = Al + (((am >> 4) * 64) + ((am & 15) | (q << 4))) * 8;
    const float* xP = x + (size_t)(m0 + am) * 2048 + kk * 512 + q * 8;

    floatx4 acc[4][4] = {};

    for (int it = 0; it < 16; ++it) {
        const float4 v0 = *(const float4*)(xP + it * 32);
        const float4 v1 = *(const float4*)(xP + it * 32 + 4);
        const int kc = kk * 16 + it;
        __syncthreads();
        const _Float16* bh_src = Wh + (size_t)kc * 16 * 512;
        const _Float16* bl_src = Wl + (size_t)kc * 16 * 512;
        #pragma unroll
        for (int i = 0; i < 4; ++i) {
            const int c = w * 4 + i;
            gload_lds16(bh_src + (size_t)c * 512 + lane * 8, Bh + c * 512);
            gload_lds16(bl_src + (size_t)c * 512 + lane * 8, Bl + c * 512);
        }
        half8 h8, l8;
        {
            const float vv[8] = {v0.x, v0.y, v0.z, v0.w, v1.x, v1.y, v1.z, v1.w};
            #pragma unroll
            for (int i = 0; i < 8; ++i) {
                const _Float16 hi = (_Float16)vv[i];
                h8[i] = hi;
                l8[i] = (_Float16)(vv[i] - (float)hi);
            }
        }
        *(half8*)AhW = h8;
        *(half8*)AlW = l8;
        __syncthreads();

        half8 ah[4], al[4], bh[4], bl[4];
        #pragma unroll
        for (int s = 0; s < 4; ++s) {
            ah[s] = *(const half8*)(Ah + (s * 64 + lane) * 8);
            al[s] = *(const half8*)(Al + (s * 64 + lane) * 8);
        }
        #pragma unroll
        for (int ni = 0; ni < 4; ++ni) {
            bh[ni] = *(const half8*)(Bh + ((w * 4 + ni) * 64 + lane) * 8);
            bl[ni] = *(const half8*)(Bl + ((w * 4 + ni) * 64 + lane) * 8);
        }
        #pragma unroll
        for (int mi = 0; mi < 4; ++mi) {
            #pragma unroll
            for (int ni = 0; ni < 4; ++ni) {
                acc[mi][ni] = __builtin_amdgcn_mfma_f32_16x16x32_f16(ah[mi], bl[ni], acc[mi][ni], 0, 0, 0);
                acc[mi][ni] = __builtin_amdgcn_mfma_f32_16x16x32_f16(al[mi], bh[ni], acc[mi][ni], 0, 0, 0);
                acc[mi][ni] = __builtin_amdgcn_mfma_f32_16x16x32_f16(ah[mi], bh[ni], acc[mi][ni], 0, 0, 0);
            }
        }
    }

    float* Pk = P + (size_t)kk * 2097152;
    #pragma unroll
    for (int mi = 0; mi < 4; ++mi) {
        #pragma unroll
        for (int ni = 0; ni < 4; ++ni) {
            const int col = w * 64 + ni * 16 + (lane & 15);
            const int rowBase = m0 + mi * 16 + (lane >> 4) * 4;
            #pragma unroll
            for (int r = 0; r < 4; ++r)
                Pk[(size_t)(rowBase + r) * 256 + col] = acc[mi][ni][r];
        }
    }
}

// ============ fused finalize + dist + softmin ===============================
// grid 256, block handles rows b0=blk*32. Reduce P (same kk order as r3),
// +bias -> femb LDS; write embh (r3 formulas, bit-identical); rebuild MFMA
// frags from femb with r3's exact hi/lo split; dist/softmin = r3 verbatim.
__global__ __launch_bounds__(256) void fin_dist(
    const float* __restrict__ P, const float* __restrict__ b_enc,
    const _Float16* __restrict__ ch, const _Float16* __restrict__ cl,
    const float* __restrict__ cnorm,
    _Float16* __restrict__ ehg, float* __restrict__ out)
{
    __shared__ float femb[32 * 257];      // later reused as D (same stride)
    __shared__ float ENORM[32], MINV[32], SUMV[32];
    const int t = threadIdx.x, lane = t & 63, w = t >> 6;
    const int b0 = blockIdx.x * 32;
    const int row = t >> 3, c8 = t & 7;   // thread: row 0..31, 32-col chunk

    // --- phase 0: reduce split-K partials (order kk=0..3, same as r3) ---
    {
        const float* p0 = P + (size_t)(b0 + row) * 256 + c8 * 32;
        float4 v[8];
        #pragma unroll
        for (int i = 0; i < 8; ++i) v[i] = *(const float4*)(p0 + i * 4);
        #pragma unroll
        for (int kk = 1; kk < 4; ++kk) {
            const float* pk = p0 + (size_t)kk * 2097152;
            #pragma unroll
            for (int i = 0; i < 8; ++i) {
                const float4 a = *(const float4*)(pk + i * 4);
                v[i].x += a.x; v[i].y += a.y; v[i].z += a.z; v[i].w += a.w;
            }
        }
        const float inv = 1.0f / 256.0f;
        float ssq = 0.0f;
        #pragma unroll
        for (int i = 0; i < 8; ++i) {
            const float4 b = *(const float4*)(b_enc + c8 * 32 + i * 4);
            float4 e;
            e.x = v[i].x * inv + b.x; e.y = v[i].y * inv + b.y;
            e.z = v[i].z * inv + b.z; e.w = v[i].w * inv + b.w;
            femb[row * 257 + c8 * 32 + i * 4 + 0] = e.x;
            femb[row * 257 + c8 * 32 + i * 4 + 1] = e.y;
            femb[row * 257 + c8 * 32 + i * 4 + 2] = e.z;
            femb[row * 257 + c8 * 32 + i * 4 + 3] = e.w;
            ssq += e.x * e.x; ssq += e.y * e.y; ssq += e.z * e.z; ssq += e.w * e.w;
        }
        ssq += __shfl_xor(ssq, 1, 64);
        ssq += __shfl_xor(ssq, 2, 64);
        ssq += __shfl_xor(ssq, 4, 64);
        if (c8 == 0) ENORM[row] = ssq;
    }
    __syncthreads();

    // --- phase 0b: write embh for recon (r3 finalize formulas) ---
    {
        const int grow = b0 + row;
        #pragma unroll
        for (int oo = 0; oo < 4; ++oo) {
            const int q = c8 * 4 + oo;
            const float* src = femb + row * 257 + q * 8;
            half8 h;
            #pragma unroll
            for (int i = 0; i < 8; ++i) h[i] = (_Float16)src[i];
            const size_t idx = (size_t)(((grow >> 4) * 8 + (q >> 2)) * 64
                                        + ((grow & 15) | ((q & 3) << 4))) * 8;
            *(half8*)(ehg + idx) = h;
        }
    }

    // --- phase 1: S via fp16x3 MFMA (frags rebuilt with r3's exact split) ---
    floatx4 acc[2][4] = {}, accX[2][4] = {};
    const int arow16 = lane & 15, aoct = lane >> 4;
    for (int kc = 0; kc < 8; ++kc) {
        half8 ah[2], al[2];
        #pragma unroll
        for (int mi = 0; mi < 2; ++mi) {
            const float* fp = femb + (mi * 16 + arow16) * 257 + kc * 32 + aoct * 8;
            #pragma unroll
            for (int j = 0; j < 8; ++j) {
                const float vv = fp[j];
                const _Float16 hi = (_Float16)vv;
                ah[mi][j] = hi;
                al[mi][j] = (_Float16)((vv - (float)hi) * 2048.0f);
            }
        }
        #pragma unroll
        for (int ni = 0; ni < 4; ++ni) {
            const size_t bb = (size_t)((kc * 16 + (w * 4 + ni)) * 64 + lane) * 8;
            const half8 bh = *(const half8*)(ch + bb);
            const half8 bl = *(const half8*)(cl + bb);
            #pragma unroll
            for (int mi = 0; mi < 2; ++mi) {
                acc[mi][ni]  = __builtin_amdgcn_mfma_f32_16x16x32_f16(ah[mi], bh, acc[mi][ni], 0, 0, 0);
                accX[mi][ni] = __builtin_amdgcn_mfma_f32_16x16x32_f16(ah[mi], bl, accX[mi][ni], 0, 0, 0);
                accX[mi][ni] = __builtin_amdgcn_mfma_f32_16x16x32_f16(al[mi], bh, accX[mi][ni], 0, 0, 0);
            }
        }
    }
    __syncthreads();   // femb reads done; reuse buffer as D

    float* D = femb;
    const float invs = 1.0f / 2048.0f;
    #pragma unroll
    for (int mi = 0; mi < 2; ++mi) {
        #pragma unroll
        for (int ni = 0; ni < 4; ++ni) {
            const int k = w * 64 + ni * 16 + (lane & 15);
            const float cn = cnorm[k];
            #pragma unroll
            for (int r = 0; r < 4; ++r) {
                const int rl = mi * 16 + (lane >> 4) * 4 + r;
                const float S = acc[mi][ni][r] + accX[mi][ni][r] * invs;
                D[rl * 257 + k] = ENORM[rl] - 2.0f * S + cn;
            }
        }
    }
    __syncthreads();

    // --- phase 2: per-row min + sum of exp (r3 verbatim) ---
    #pragma unroll
    for (int rr = 0; rr < 8; ++rr) {
        const int r = w * 8 + rr;
        const float d0 = D[r * 257 + lane +   0];
        const float d1 = D[r * 257 + lane +  64];
        const float d2 = D[r * 257 + lane + 128];
        const float d3 = D[r * 257 + lane + 192];
        float mn = fminf(fminf(d0, d1), fminf(d2, d3));
        #pragma unroll
        for (int off = 32; off >= 1; off >>= 1) mn = fminf(mn, __shfl_xor(mn, off, 64));
        float s = expf(-ALPHA_F * (d0 - mn)) + expf(-ALPHA_F * (d1 - mn))
                + expf(-ALPHA_F * (d2 - mn)) + expf(-ALPHA_F * (d3 - mn));
        #pragma unroll
        for (int off = 32; off >= 1; off >>= 1) s += __shfl_xor(s, off, 64);
        if (lane == 0) { MINV[r] = mn; SUMV[r] = s; }
    }
    __syncthreads();

    // --- phase 3: weighted writes (r3 verbatim) ---
    const int b = t & 31, kg = t >> 5;
    const float mn = MINV[b], sv = SUMV[b];
    #pragma unroll
    for (int kk = 0; kk < 32; ++kk) {
        const int k = kk * 8 + kg;
        const float dv = D[b * 257 + k];
        out[(size_t)k * 8192 + b0 + b] = dv * expf(-ALPHA_F * (dv - mn)) / sv;
    }
}

// ============ recon = emb @ W_dec + b_dec (r3 verbatim) =====================
__global__ __launch_bounds__(256) void recon_gemm(
    const _Float16* __restrict__ embh, const _Float16* __restrict__ Wdh,
    const float* __restrict__ b_dec, float* __restrict__ out)
{
    __shared__ _Float16 Ah[8 * 64 * 8];   // 8KB
    __shared__ _Float16 Bh[8 * 64 * 8];   // 8KB
    const int t = threadIdx.x, lane = t & 63, w = t >> 6;
    const int wm = w >> 1, wn = w & 1;
    const int nb = blockIdx.x, mb = blockIdx.y;

    floatx4 acc[4][4] = {};

    for (int kc = 0; kc < 8; ++kc) {
        __syncthreads();
        #pragma unroll
        for (int i = 0; i < 2; ++i) {
            const int c = w * 2 + i;
            gload_lds16(embh + (size_t)(((mb * 8 + c) * 8 + kc) * 64 + lane) * 8, Ah + c * 512);
            gload_lds16(Wdh + (size_t)((kc * 128 + nb * 8 + c) * 64 + lane) * 8, Bh + c * 512);
        }
        __syncthreads();
        half8 a[4], b[4];
        #pragma unroll
        for (int mi = 0; mi < 4; ++mi) a[mi] = *(const half8*)(Ah + ((wm * 4 + mi) * 64 + lane) * 8);
        #pragma unroll
        for (int ni = 0; ni < 4; ++ni) b[ni] = *(const half8*)(Bh + ((wn * 4 + ni) * 64 + lane) * 8);
        #pragma unroll
        for (int mi = 0; mi < 4; ++mi)
            #pragma unroll
            for (int ni = 0; ni < 4; ++ni)
                acc[mi][ni] = __builtin_amdgcn_mfma_f32_16x16x32_f16(a[mi], b[ni], acc[mi][ni], 0, 0, 0);
    }

    #pragma unroll
    for (int ni = 0; ni < 4; ++ni) {
        const int col = nb * 128 + (wn * 4 + ni) * 16 + (lane & 15);
        const float bias = b_dec[col];
        #pragma unroll
        for (int mi = 0; mi < 4; ++mi) {
            const int rowBase = mb * 128 + (wm * 4 + mi) * 16 + (lane >> 4) * 4;
            #pragma unroll
            for (int r = 0; r < 4; ++r)
                out[(size_t)(rowBase + r) * 2048 + col] = acc[mi][ni][r] + bias;
        }
    }
}

// ================= launch ==================================================
extern "C" void kernel_launch(void* const* d_in, const int* in_sizes, int n_in,
                              void* d_out, int out_size, void* d_ws, size_t ws_size,
                              hipStream_t stream) {
    const float* x     = (const float*)d_in[0];   // [8192,2048]
    const float* W_enc = (const float*)d_in[1];   // [2048,256]
    const float* b_enc = (const float*)d_in[2];   // [256]
    const float* W_dec = (const float*)d_in[3];   // [256,2048]
    const float* b_dec = (const float*)d_in[4];   // [2048]
    const float* creps = (const float*)d_in[5];   // [256,256]

    float* out_w   = (float*)d_out;               // [256,8192]
    float* out_rec = out_w + (size_t)256 * 8192;  // [8192,2048]
    float* P       = out_rec;                     // split-K partials (32MB of 64MB)

    float*     cnorm = (float*)d_ws;                       // 1 KB
    _Float16*  embh  = (_Float16*)(cnorm + 256);           // 4 MB, frag-order
    _Float16*  Whf   = embh + (size_t)8192 * 256;          // 1 MB
    _Float16*  Wlf   = Whf + (size_t)2048 * 256;           // 1 MB
    _Float16*  Wdh   = Wlf + (size_t)2048 * 256;           // 1 MB
    _Float16*  crh   = Wdh + (size_t)256 * 2048;           // 128 KB
    _Float16*  crl   = crh + (size_t)256 * 256;            // 128 KB

    // all input preprocessing in one launch
    prep<<<608, 256, 0, stream>>>(W_enc, W_dec, creps, Whf, Wlf, Wdh, crh, crl, cnorm);

    // emb partial sums (split-K=4, r3-exact) into out_rec scratch region
    emb_gemm<<<dim3(4, 128), 256, 0, stream>>>(x, Whf, Wlf, P);

    // fused finalize + dist + softmin: writes out_w (output 0) + embh
    fin_dist<<<256, 256, 0, stream>>>(P, b_enc, crh, crl, cnorm, embh, out_w);

    // reconstruction (output 1) — overwrites the partials region
    recon_gemm<<<dim3(16, 64), 256, 0, stream>>>(embh, Wdh, b_dec, out_rec);
}

// Round 7
// 199.334 us; speedup vs baseline: 1.1385x; 1.0249x over previous
//
#include <hip/hip_runtime.h>

#define ALPHA_F 1000.0f

typedef _Float16 half8 __attribute__((ext_vector_type(8)));
typedef float floatx4 __attribute__((ext_vector_type(4)));

__device__ __forceinline__ void gload_lds16(const void* g, void* l) {
    __builtin_amdgcn_global_load_lds(
        (const __attribute__((address_space(1))) unsigned int*)g,
        (__attribute__((address_space(3))) unsigned int*)l, 16, 0, 0);
}

// ============ fused prep: W_enc/W_dec/creps splits + cnorm (r6 verbatim) ====
__global__ __launch_bounds__(256) void prep(
    const float* __restrict__ W_enc, const float* __restrict__ W_dec,
    const float* __restrict__ creps,
    _Float16* __restrict__ Wh, _Float16* __restrict__ Wl,
    _Float16* __restrict__ Wdh,
    _Float16* __restrict__ Ch, _Float16* __restrict__ Cl,
    float* __restrict__ cnorm)
{
    const int bid = blockIdx.x;
    if (bid < 256) {
        const int q = bid * 256 + threadIdx.x;
        const int n = q & 255, k8 = q >> 8;
        const int k = k8 * 8;
        half8 h, l;
        #pragma unroll
        for (int i = 0; i < 8; ++i) {
            const float v = W_enc[(size_t)(k + i) * 256 + n] * 256.0f;
            const _Float16 hi = (_Float16)v;
            h[i] = hi;
            l[i] = (_Float16)(v - (float)hi);
        }
        const int kc = k >> 5, nt = n >> 4;
        const int lane = (n & 15) | ((k8 & 3) << 4);
        const size_t idx = (size_t)((kc * 16 + nt) * 64 + lane) * 8;
        *(half8*)(Wh + idx) = h;
        *(half8*)(Wl + idx) = l;
    } else if (bid < 512) {
        const int q = (bid - 256) * 256 + threadIdx.x;
        const int n = q & 2047, k8 = q >> 11;
        const int k = k8 * 8;
        half8 h;
        #pragma unroll
        for (int i = 0; i < 8; ++i) h[i] = (_Float16)W_dec[(size_t)(k + i) * 2048 + n];
        const int kc = k8 >> 2, nt = n >> 4;
        const int lane = (n & 15) | ((k8 & 3) << 4);
        *(half8*)(Wdh + (size_t)((kc * 128 + nt) * 64 + lane) * 8) = h;
    } else if (bid < 544) {
        const int q = (bid - 512) * 256 + threadIdx.x;
        const int n = q & 255, j8 = q >> 8;
        const int j = j8 * 8;
        half8 h, l;
        #pragma unroll
        for (int i = 0; i < 8; ++i) {
            const float v = creps[(size_t)n * 256 + j + i];
            const _Float16 hi = (_Float16)v;
            h[i] = hi;
            l[i] = (_Float16)((v - (float)hi) * 2048.0f);
        }
        const int jc = j >> 5, nt = n >> 4;
        const int lane = (n & 15) | ((j8 & 3) << 4);
        const size_t idx = (size_t)((jc * 16 + nt) * 64 + lane) * 8;
        *(half8*)(Ch + idx) = h;
        *(half8*)(Cl + idx) = l;
    } else {
        const int wid = threadIdx.x >> 6, lane = threadIdx.x & 63;
        const int row = (bid - 544) * 4 + wid;
        const float4 v = *(const float4*)(creps + (size_t)row * 256 + lane * 4);
        float s = v.x * v.x + v.y * v.y + v.z * v.z + v.w * v.w;
        #pragma unroll
        for (int off = 32; off >= 1; off >>= 1) s += __shfl_xor(s, off, 64);
        if (lane == 0) cnorm[row] = s;
    }
}

// ============ emb partials (r3 verbatim — bit-validated) ====================
__global__ __launch_bounds__(256) void emb_gemm(
    const float* __restrict__ x, const _Float16* __restrict__ Wh,
    const _Float16* __restrict__ Wl, float* __restrict__ P)
{
    __shared__ _Float16 Ah[4 * 64 * 8], Al[4 * 64 * 8];
    __shared__ _Float16 Bh[16 * 64 * 8], Bl[16 * 64 * 8];
    const int t = threadIdx.x, lane = t & 63, w = t >> 6;
    const int kk = blockIdx.x;
    const int mb = blockIdx.y;
    const int m0 = mb * 64;

    const int am = t >> 2, q = t & 3;
    _Float16* AhW = Ah + (((am >> 4) * 64) + ((am & 15) | (q << 4))) * 8;
    _Float16* AlW = Al + (((am >> 4) * 64) + ((am & 15) | (q << 4))) * 8;
    const float* xP = x + (size_t)(m0 + am) * 2048 + kk * 512 + q * 8;

    floatx4 acc[4][4] = {};

    for (int it = 0; it < 16; ++it) {
        const float4 v0 = *(const float4*)(xP + it * 32);
        const float4 v1 = *(const float4*)(xP + it * 32 + 4);
        const int kc = kk * 16 + it;
        __syncthreads();
        const _Float16* bh_src = Wh + (size_t)kc * 16 * 512;
        const _Float16* bl_src = Wl + (size_t)kc * 16 * 512;
        #pragma unroll
        for (int i = 0; i < 4; ++i) {
            const int c = w * 4 + i;
            gload_lds16(bh_src + (size_t)c * 512 + lane * 8, Bh + c * 512);
            gload_lds16(bl_src + (size_t)c * 512 + lane * 8, Bl + c * 512);
        }
        half8 h8, l8;
        {
            const float vv[8] = {v0.x, v0.y, v0.z, v0.w, v1.x, v1.y, v1.z, v1.w};
            #pragma unroll
            for (int i = 0; i < 8; ++i) {
                const _Float16 hi = (_Float16)vv[i];
                h8[i] = hi;
                l8[i] = (_Float16)(vv[i] - (float)hi);
            }
        }
        *(half8*)AhW = h8;
        *(half8*)AlW = l8;
        __syncthreads();

        half8 ah[4], al[4], bh[4], bl[4];
        #pragma unroll
        for (int s = 0; s < 4; ++s) {
            ah[s] = *(const half8*)(Ah + (s * 64 + lane) * 8);
            al[s] = *(const half8*)(Al + (s * 64 + lane) * 8);
        }
        #pragma unroll
        for (int ni = 0; ni < 4; ++ni) {
            bh[ni] = *(const half8*)(Bh + ((w * 4 + ni) * 64 + lane) * 8);
            bl[ni] = *(const half8*)(Bl + ((w * 4 + ni) * 64 + lane) * 8);
        }
        #pragma unroll
        for (int mi = 0; mi < 4; ++mi) {
            #pragma unroll
            for (int ni = 0; ni < 4; ++ni) {
                acc[mi][ni] = __builtin_amdgcn_mfma_f32_16x16x32_f16(ah[mi], bl[ni], acc[mi][ni], 0, 0, 0);
                acc[mi][ni] = __builtin_amdgcn_mfma_f32_16x16x32_f16(al[mi], bh[ni], acc[mi][ni], 0, 0, 0);
                acc[mi][ni] = __builtin_amdgcn_mfma_f32_16x16x32_f16(ah[mi], bh[ni], acc[mi][ni], 0, 0, 0);
            }
        }
    }

    float* Pk = P + (size_t)kk * 2097152;
    #pragma unroll
    for (int mi = 0; mi < 4; ++mi) {
        #pragma unroll
        for (int ni = 0; ni < 4; ++ni) {
            const int col = w * 64 + ni * 16 + (lane & 15);
            const int rowBase = m0 + mi * 16 + (lane >> 4) * 4;
            #pragma unroll
            for (int r = 0; r < 4; ++r)
                Pk[(size_t)(rowBase + r) * 256 + col] = acc[mi][ni][r];
        }
    }
}

// ============ finalize (standalone, LDS-free, streaming) ====================
// grid 256: block handles rows b0=blk*32; thread: row=t>>3, cols c8*32..+31.
// Reduce order, ssq order (32 seq cols + xor 1,2,4 over 8 thr/row), embh
// formulas all bit-identical to r6 phase 0/0b. Adds embf fp32 store.
__global__ __launch_bounds__(256) void finalize(
    const float* __restrict__ P, const float* __restrict__ b_enc,
    _Float16* __restrict__ ehg, float* __restrict__ embf,
    float* __restrict__ enorm)
{
    const int t = threadIdx.x;
    const int b0 = blockIdx.x * 32;
    const int row = t >> 3, c8 = t & 7;
    const int grow = b0 + row;

    const float* p0 = P + (size_t)grow * 256 + c8 * 32;
    float4 v[8];
    #pragma unroll
    for (int i = 0; i < 8; ++i) v[i] = *(const float4*)(p0 + i * 4);
    #pragma unroll
    for (int kk = 1; kk < 4; ++kk) {
        const float* pk = p0 + (size_t)kk * 2097152;
        #pragma unroll
        for (int i = 0; i < 8; ++i) {
            const float4 a = *(const float4*)(pk + i * 4);
            v[i].x += a.x; v[i].y += a.y; v[i].z += a.z; v[i].w += a.w;
        }
    }
    const float inv = 1.0f / 256.0f;
    float e[32];
    float ssq = 0.0f;
    #pragma unroll
    for (int i = 0; i < 8; ++i) {
        const float4 b = *(const float4*)(b_enc + c8 * 32 + i * 4);
        e[i * 4 + 0] = v[i].x * inv + b.x;
        e[i * 4 + 1] = v[i].y * inv + b.y;
        e[i * 4 + 2] = v[i].z * inv + b.z;
        e[i * 4 + 3] = v[i].w * inv + b.w;
        ssq += e[i * 4 + 0] * e[i * 4 + 0];
        ssq += e[i * 4 + 1] * e[i * 4 + 1];
        ssq += e[i * 4 + 2] * e[i * 4 + 2];
        ssq += e[i * 4 + 3] * e[i * 4 + 3];
    }
    // embf fp32 (row-major) — same bits the old path put in LDS
    #pragma unroll
    for (int i = 0; i < 8; ++i) {
        float4 s4;
        s4.x = e[i * 4 + 0]; s4.y = e[i * 4 + 1];
        s4.z = e[i * 4 + 2]; s4.w = e[i * 4 + 3];
        *(float4*)(embf + (size_t)grow * 256 + c8 * 32 + i * 4) = s4;
    }
    // embh (r3/r6 formulas, bit-identical)
    #pragma unroll
    for (int oo = 0; oo < 4; ++oo) {
        const int q = c8 * 4 + oo;
        half8 h;
        #pragma unroll
        for (int i = 0; i < 8; ++i) h[i] = (_Float16)e[oo * 8 + i];
        const size_t idx = (size_t)(((grow >> 4) * 8 + (q >> 2)) * 64
                                    + ((grow & 15) | ((q & 3) << 4))) * 8;
        *(half8*)(ehg + idx) = h;
    }
    ssq += __shfl_xor(ssq, 1, 64);
    ssq += __shfl_xor(ssq, 2, 64);
    ssq += __shfl_xor(ssq, 4, 64);
    if (c8 == 0) enorm[grow] = ssq;
}

// ============ dist + softmin, 16 rows/block, grid 512 =======================
// A-frags rebuilt from embf with r6's exact hi/lo split; MFMA chains, D,
// min/sum, and weighted-write arithmetic bit-identical to r6 (mappings only).
__global__ __launch_bounds__(256) void dist16(
    const float* __restrict__ embf, const _Float16* __restrict__ ch,
    const _Float16* __restrict__ cl, const float* __restrict__ enorm,
    const float* __restrict__ cnorm, float* __restrict__ out)
{
    __shared__ float D[16 * 257];
    __shared__ float MINV[16], SUMV[16];
    const int t = threadIdx.x, lane = t & 63, w = t >> 6;
    const int b0 = blockIdx.x * 16;
    const int arow16 = lane & 15, aoct = lane >> 4;

    floatx4 acc[4] = {}, accX[4] = {};
    for (int kc = 0; kc < 8; ++kc) {
        const float* fp = embf + (size_t)(b0 + arow16) * 256 + kc * 32 + aoct * 8;
        const float4 u0 = *(const float4*)(fp);
        const float4 u1 = *(const float4*)(fp + 4);
        const float vv[8] = {u0.x, u0.y, u0.z, u0.w, u1.x, u1.y, u1.z, u1.w};
        half8 ah, al;
        #pragma unroll
        for (int j = 0; j < 8; ++j) {
            const _Float16 hi = (_Float16)vv[j];
            ah[j] = hi;
            al[j] = (_Float16)((vv[j] - (float)hi) * 2048.0f);
        }
        #pragma unroll
        for (int ni = 0; ni < 4; ++ni) {
            const size_t bb = (size_t)((kc * 16 + (w * 4 + ni)) * 64 + lane) * 8;
            const half8 bh = *(const half8*)(ch + bb);
            const half8 bl = *(const half8*)(cl + bb);
            acc[ni]  = __builtin_amdgcn_mfma_f32_16x16x32_f16(ah, bh, acc[ni], 0, 0, 0);
            accX[ni] = __builtin_amdgcn_mfma_f32_16x16x32_f16(ah, bl, accX[ni], 0, 0, 0);
            accX[ni] = __builtin_amdgcn_mfma_f32_16x16x32_f16(al, bh, accX[ni], 0, 0, 0);
        }
    }

    const float invs = 1.0f / 2048.0f;
    #pragma unroll
    for (int ni = 0; ni < 4; ++ni) {
        const int k = w * 64 + ni * 16 + (lane & 15);
        const float cn = cnorm[k];
        #pragma unroll
        for (int r = 0; r < 4; ++r) {
            const int rl = (lane >> 4) * 4 + r;
            const float S = acc[ni][r] + accX[ni][r] * invs;
            D[rl * 257 + k] = enorm[b0 + rl] - 2.0f * S + cn;
        }
    }
    __syncthreads();

    #pragma unroll
    for (int rr = 0; rr < 4; ++rr) {
        const int r = w * 4 + rr;
        const float d0 = D[r * 257 + lane +   0];
        const float d1 = D[r * 257 + lane +  64];
        const float d2 = D[r * 257 + lane + 128];
        const float d3 = D[r * 257 + lane + 192];
        float mn = fminf(fminf(d0, d1), fminf(d2, d3));
        #pragma unroll
        for (int off = 32; off >= 1; off >>= 1) mn = fminf(mn, __shfl_xor(mn, off, 64));
        float s = expf(-ALPHA_F * (d0 - mn)) + expf(-ALPHA_F * (d1 - mn))
                + expf(-ALPHA_F * (d2 - mn)) + expf(-ALPHA_F * (d3 - mn));
        #pragma unroll
        for (int off = 32; off >= 1; off >>= 1) s += __shfl_xor(s, off, 64);
        if (lane == 0) { MINV[r] = mn; SUMV[r] = s; }
    }
    __syncthreads();

    const int b = t & 15, kg = t >> 4;
    const float mn = MINV[b], sv = SUMV[b];
    #pragma unroll
    for (int kk = 0; kk < 16; ++kk) {
        const int k = kk * 16 + kg;
        const float dv = D[b * 257 + k];
        out[(size_t)k * 8192 + b0 + b] = dv * expf(-ALPHA_F * (dv - mn)) / sv;
    }
}

// ============ recon = emb @ W_dec + b_dec (r3 verbatim) =====================
__global__ __launch_bounds__(256) void recon_gemm(
    const _Float16* __restrict__ embh, const _Float16* __restrict__ Wdh,
    const float* __restrict__ b_dec, float* __restrict__ out)
{
    __shared__ _Float16 Ah[8 * 64 * 8];
    __shared__ _Float16 Bh[8 * 64 * 8];
    const int t = threadIdx.x, lane = t & 63, w = t >> 6;
    const int wm = w >> 1, wn = w & 1;
    const int nb = blockIdx.x, mb = blockIdx.y;

    floatx4 acc[4][4] = {};

    for (int kc = 0; kc < 8; ++kc) {
        __syncthreads();
        #pragma unroll
        for (int i = 0; i < 2; ++i) {
            const int c = w * 2 + i;
            gload_lds16(embh + (size_t)(((mb * 8 + c) * 8 + kc) * 64 + lane) * 8, Ah + c * 512);
            gload_lds16(Wdh + (size_t)((kc * 128 + nb * 8 + c) * 64 + lane) * 8, Bh + c * 512);
        }
        __syncthreads();
        half8 a[4], b[4];
        #pragma unroll
        for (int mi = 0; mi < 4; ++mi) a[mi] = *(const half8*)(Ah + ((wm * 4 + mi) * 64 + lane) * 8);
        #pragma unroll
        for (int ni = 0; ni < 4; ++ni) b[ni] = *(const half8*)(Bh + ((wn * 4 + ni) * 64 + lane) * 8);
        #pragma unroll
        for (int mi = 0; mi < 4; ++mi)
            #pragma unroll
            for (int ni = 0; ni < 4; ++ni)
                acc[mi][ni] = __builtin_amdgcn_mfma_f32_16x16x32_f16(a[mi], b[ni], acc[mi][ni], 0, 0, 0);
    }

    #pragma unroll
    for (int ni = 0; ni < 4; ++ni) {
        const int col = nb * 128 + (wn * 4 + ni) * 16 + (lane & 15);
        const float bias = b_dec[col];
        #pragma unroll
        for (int mi = 0; mi < 4; ++mi) {
            const int rowBase = mb * 128 + (wm * 4 + mi) * 16 + (lane >> 4) * 4;
            #pragma unroll
            for (int r = 0; r < 4; ++r)
                out[(size_t)(rowBase + r) * 2048 + col] = acc[mi][ni][r] + bias;
        }
    }
}

// ================= launch ==================================================
extern "C" void kernel_launch(void* const* d_in, const int* in_sizes, int n_in,
                              void* d_out, int out_size, void* d_ws, size_t ws_size,
                              hipStream_t stream) {
    const float* x     = (const float*)d_in[0];   // [8192,2048]
    const float* W_enc = (const float*)d_in[1];   // [2048,256]
    const float* b_enc = (const float*)d_in[2];   // [256]
    const float* W_dec = (const float*)d_in[3];   // [256,2048]
    const float* b_dec = (const float*)d_in[4];   // [2048]
    const float* creps = (const float*)d_in[5];   // [256,256]

    float* out_w   = (float*)d_out;               // [256,8192]
    float* out_rec = out_w + (size_t)256 * 8192;  // [8192,2048]
    float* P       = out_rec;                     // split-K partials (32MB of 64MB)

    float*     cnorm = (float*)d_ws;                       // 1 KB
    _Float16*  embh  = (_Float16*)(cnorm + 256);           // 4 MB, frag-order
    _Float16*  Whf   = embh + (size_t)8192 * 256;          // 1 MB
    _Float16*  Wlf   = Whf + (size_t)2048 * 256;           // 1 MB
    _Float16*  Wdh   = Wlf + (size_t)2048 * 256;           // 1 MB
    _Float16*  crh   = Wdh + (size_t)256 * 2048;           // 128 KB
    _Float16*  crl   = crh + (size_t)256 * 256;            // 128 KB
    float*     enorm = (float*)(crl + (size_t)256 * 256);  // 32 KB
    float*     embf  = enorm + 8192;                       // 8 MB fp32 row-major

    // all input preprocessing in one launch
    prep<<<608, 256, 0, stream>>>(W_enc, W_dec, creps, Whf, Wlf, Wdh, crh, crl, cnorm);

    // emb partial sums (split-K=4, r3-exact) into out_rec scratch region
    emb_gemm<<<dim3(4, 128), 256, 0, stream>>>(x, Whf, Wlf, P);

    // reduce + bias -> embf/embh/enorm (streaming, no barriers)
    finalize<<<256, 256, 0, stream>>>(P, b_enc, embh, embf, enorm);

    // weighted_dist (output 0), 512 blocks
    dist16<<<512, 256, 0, stream>>>(embf, crh, crl, enorm, cnorm, out_w);

    // reconstruction (output 1) — overwrites the partials region
    recon_gemm<<<dim3(16, 64), 256, 0, stream>>>(embh, Wdh, b_dec, out_rec);
}